// Round 2
// baseline (34.871 us; speedup 1.0000x reference)
//
#include <hip/hip_runtime.h>

#define BATCH 2048
#define INF_  512
#define OUTF  256

// async global->LDS, 16B/lane; LDS dst must be wave-uniform (HW adds lane*16)
__device__ __forceinline__ void gload16(const float* src, float* dst_lds) {
  __builtin_amdgcn_global_load_lds((const __attribute__((address_space(1))) void*)src,
                                   (__attribute__((address_space(3))) void*)dst_lds,
                                   16, 0, 0);
}

#define MAX3(d, s1, s2) asm("v_max3_f32 %0, %0, %1, %2" : "+v"(d) : "v"(s1), "v"(s2))

// Single-wave block (64 threads), tile 64 rows x 64 cols, per-thread 8x8, BK=32.
// NO __syncthreads anywhere: wave-private pipeline, counted vmcnt waits only.
// A LDS [64][32] XOR-swizzled (granule(m,q) holds A[m][4*(q ^ ((m>>3)&7))]) ->
//   conflict-free b128 reads. B LDS [32][64] linear -> broadcast + 2-way (free).
template <int T, bool DIRECT>
__global__ __launch_bounds__(64, 1) void crisp_partial(const float* __restrict__ M,
                                                       const float* __restrict__ W,
                                                       float* __restrict__ out) {
  __shared__ __align__(16) float lsA[2][64 * 32];
  __shared__ __align__(16) float lsB[2][32 * 64];

  const int lane = threadIdx.x;      // 0..63, single wave
  const int mg   = lane >> 3;        // row group 0..7
  const int og   = lane & 7;         // col group 0..7
  const int row0 = blockIdx.y * 64;
  const int col0 = blockIdx.x * 64;
  const int kb0  = blockIdx.z * (T * 32);

  float acc[8][8];
#pragma unroll
  for (int r = 0; r < 8; r++)
#pragma unroll
    for (int c = 0; c < 8; c++) acc[r][c] = -1e30f;

  auto stage = [&](int buf, int kb) {
    // A: 512 granules of 16B; granule p holds A[m][4*q_src], m=p>>3,
    // q_src=(p&7)^((p>>6)&7)  (inverse of read-side XOR swizzle)
#pragma unroll
    for (int i = 0; i < 8; i++) {
      int p  = i * 64 + lane;
      int m  = p >> 3;
      int q  = (p & 7) ^ ((p >> 6) & 7);
      gload16(M + (size_t)(row0 + m) * INF_ + kb + q * 4, &lsA[buf][i * 256]);
    }
    // B: linear; granule p holds W[kb+(p>>4)][col0+4*(p&15)]
#pragma unroll
    for (int i = 0; i < 8; i++) {
      int p = i * 64 + lane;
      int k = p >> 4;
      int c = p & 15;
      gload16(W + (size_t)(kb + k) * OUTF + col0 + c * 4, &lsB[buf][i * 256]);
    }
  };

  auto compute = [&](int buf) {
    const float* As = lsA[buf];
    const float* Bs = lsB[buf];
#pragma unroll
    for (int kq = 0; kq < 8; kq++) {
      float a[8][4];
#pragma unroll
      for (int r = 0; r < 8; r++) {
        float4 v = *reinterpret_cast<const float4*>(
            &As[(mg * 8 + r) * 32 + ((kq ^ mg) << 2)]);
        a[r][0] = v.x; a[r][1] = v.y; a[r][2] = v.z; a[r][3] = v.w;
      }
      float bb[4][8];
#pragma unroll
      for (int j = 0; j < 4; j++) {
#pragma unroll
        for (int h = 0; h < 2; h++) {
          float4 v = *reinterpret_cast<const float4*>(
              &Bs[(kq * 4 + j) * 64 + og * 8 + h * 4]);
          bb[j][h * 4 + 0] = v.x; bb[j][h * 4 + 1] = v.y;
          bb[j][h * 4 + 2] = v.z; bb[j][h * 4 + 3] = v.w;
        }
      }
#pragma unroll
      for (int r = 0; r < 8; r++)
#pragma unroll
        for (int c = 0; c < 8; c++) {
          float t0 = fminf(a[r][0], bb[0][c]);
          float t1 = fminf(a[r][1], bb[1][c]);
          float t2 = fminf(a[r][2], bb[2][c]);
          float t3 = fminf(a[r][3], bb[3][c]);
          MAX3(acc[r][c], t0, t1);
          MAX3(acc[r][c], t2, t3);
        }
    }
  };

  stage(0, kb0);
  if (T > 1) stage(1, kb0 + 32);

#pragma unroll
  for (int t = 0; t < T; ++t) {
    if (t + 1 < T) {
      asm volatile("s_waitcnt vmcnt(16)" ::: "memory");  // current buf landed, next in flight
    } else {
      asm volatile("s_waitcnt vmcnt(0)" ::: "memory");
    }
    compute(t & 1);
    if (t + 2 < T) {
      asm volatile("" ::: "memory");                     // keep reads of buf before its reuse
      stage(t & 1, kb0 + (t + 2) * 32);
    }
  }

  float* pout = DIRECT ? out : out + (size_t)blockIdx.z * (BATCH * OUTF);
  const int orow = row0 + mg * 8;
  const int ocol = col0 + og * 8;
#pragma unroll
  for (int r = 0; r < 8; r++) {
    float4 v0 = make_float4(acc[r][0], acc[r][1], acc[r][2], acc[r][3]);
    float4 v1 = make_float4(acc[r][4], acc[r][5], acc[r][6], acc[r][7]);
    *reinterpret_cast<float4*>(&pout[(size_t)(orow + r) * OUTF + ocol])     = v0;
    *reinterpret_cast<float4*>(&pout[(size_t)(orow + r) * OUTF + ocol + 4]) = v1;
  }
}

__global__ __launch_bounds__(256) void crisp_combine(const float* __restrict__ part,
                                                     float* __restrict__ out, int KS) {
  int i = (blockIdx.x * 256 + threadIdx.x) * 4;
  float4 v = *reinterpret_cast<const float4*>(&part[i]);
  for (int ks = 1; ks < KS; ++ks) {
    float4 u = *reinterpret_cast<const float4*>(&part[(size_t)ks * (BATCH * OUTF) + i]);
    v.x = fmaxf(v.x, u.x); v.y = fmaxf(v.y, u.y);
    v.z = fmaxf(v.z, u.z); v.w = fmaxf(v.w, u.w);
  }
  *reinterpret_cast<float4*>(&out[i]) = v;
}

extern "C" void kernel_launch(void* const* d_in, const int* in_sizes, int n_in,
                              void* d_out, int out_size, void* d_ws, size_t ws_size,
                              hipStream_t stream) {
  const float* M = (const float*)d_in[0];
  const float* W = (const float*)d_in[1];
  float* out = (float*)d_out;

  const size_t plane = (size_t)BATCH * OUTF * sizeof(float);
  if (ws_size >= 8 * plane) {
    dim3 grid(OUTF / 64, BATCH / 64, 8);  // 1024 blocks = 4 blocks/CU
    crisp_partial<2, false><<<grid, 64, 0, stream>>>(M, W, (float*)d_ws);
    crisp_combine<<<(BATCH * OUTF / 4) / 256, 256, 0, stream>>>((const float*)d_ws, out, 8);
  } else {
    dim3 grid(OUTF / 64, BATCH / 64, 1);  // fallback: direct, K-loop in-block
    crisp_partial<16, true><<<grid, 64, 0, stream>>>(M, W, out);
  }
}

// Round 4
// 27.135 us; speedup vs baseline: 1.2851x; 1.2851x over previous
//
#include <hip/hip_runtime.h>

typedef unsigned int uint;
typedef unsigned short ushort;

#define BATCH 2048
#define INF_  512
#define OUTF  256
#define KS    8
#define KPER  64   // INF_/KS
#define BM    32
#define BO    64
#define BK    32

// ws layout (bytes): A16 | W16T | partials(f16)
#define A16_OFF  0
#define W16T_OFF ((size_t)BATCH * INF_ * 2)                  // 2 MB
#define PART_OFF (W16T_OFF + (size_t)OUTF * INF_ * 2)        // +256 KB
#define WS_NEED  (PART_OFF + (size_t)KS * BATCH * OUTF * 2)  // ~10.25 MB

__device__ __forceinline__ void gload16(const void* src, void* dst_lds) {
  __builtin_amdgcn_global_load_lds((const __attribute__((address_space(1))) void*)src,
                                   (__attribute__((address_space(3))) void*)dst_lds,
                                   16, 0, 0);
}

#define PKMIN(d, a, b) asm("v_pk_min_f16 %0, %1, %2" : "=v"(d) : "v"(a), "v"(b))
#define PKMAX(d, a, b) asm("v_pk_max_f16 %0, %1, %2" : "=v"(d) : "v"(a), "v"(b))
#define PKMAXA(d, a)   asm("v_pk_max_f16 %0, %0, %1" : "+v"(d) : "v"(a))

static __device__ __forceinline__ uint pkrtz(float a, float b) {
  typedef __fp16 half2_t __attribute__((ext_vector_type(2)));
  half2_t h = __builtin_amdgcn_cvt_pkrtz(a, b);
  return __builtin_bit_cast(uint, h);
}
static __device__ __forceinline__ float h2f(uint u) {
  __fp16 h = __builtin_bit_cast(__fp16, (ushort)(u & 0xFFFF));
  return (float)h;
}

// ---- pass 1: convert M -> f16 (row-major) and W -> f16 TRANSPOSED [o][k] ----
__global__ __launch_bounds__(256) void crisp_convert(const float* __restrict__ M,
                                                     const float* __restrict__ W,
                                                     ushort* __restrict__ A16,
                                                     ushort* __restrict__ W16T) {
  if (blockIdx.x < 512) {
    int gid = blockIdx.x * 256 + threadIdx.x;      // 131072 threads x 8 elems
    const float4* src = (const float4*)M;
    float4 v0 = src[gid * 2], v1 = src[gid * 2 + 1];
    uint4 o;
    o.x = pkrtz(v0.x, v0.y); o.y = pkrtz(v0.z, v0.w);
    o.z = pkrtz(v1.x, v1.y); o.w = pkrtz(v1.z, v1.w);
    ((uint4*)A16)[gid] = o;
  } else {
    // transpose one 64x64 tile of W (512x256) through LDS
    int id = blockIdx.x - 512;                     // 0..31
    int kt = id >> 2, ot = id & 3;
    __shared__ ushort tile[64][72];                // +8 pad
    int t = threadIdx.x;
    int r = t >> 2, c0 = (t & 3) * 16;
    const float* wp = W + (size_t)(kt * 64 + r) * OUTF + ot * 64 + c0;
    float4 w0 = *(const float4*)(wp);
    float4 w1 = *(const float4*)(wp + 4);
    float4 w2 = *(const float4*)(wp + 8);
    float4 w3 = *(const float4*)(wp + 12);
    uint p0 = pkrtz(w0.x, w0.y), p1 = pkrtz(w0.z, w0.w);
    uint p2 = pkrtz(w1.x, w1.y), p3 = pkrtz(w1.z, w1.w);
    uint p4 = pkrtz(w2.x, w2.y), p5 = pkrtz(w2.z, w2.w);
    uint p6 = pkrtz(w3.x, w3.y), p7 = pkrtz(w3.z, w3.w);
    uint ps[8] = {p0, p1, p2, p3, p4, p5, p6, p7};
#pragma unroll
    for (int j = 0; j < 8; j++) {
      tile[r][c0 + 2 * j]     = (ushort)(ps[j] & 0xFFFF);
      tile[r][c0 + 2 * j + 1] = (ushort)(ps[j] >> 16);
    }
    __syncthreads();
    int o = t >> 2, k0 = (t & 3) * 16;
    uint w[8];
#pragma unroll
    for (int j = 0; j < 8; j++)
      w[j] = (uint)tile[k0 + 2 * j][o] | ((uint)tile[k0 + 2 * j + 1][o] << 16);
    ushort* dst = W16T + (size_t)(ot * 64 + o) * INF_ + kt * 64 + k0;
    *(uint4*)dst       = make_uint4(w[0], w[1], w[2], w[3]);
    *(uint4*)(dst + 8) = make_uint4(w[4], w[5], w[6], w[7]);
  }
}

// ---- pass 2: tropical partials in packed f16 ----
// 1-wave block, tile BM=32 x BO=64, per-thread 4x8, BK=32, K=64 per block.
// LDS granules (16B = 8 f16) XOR-swizzled: A slot = kq ^ ((row>>2)&3),
// B slot = kq ^ ((col>>3)&3)  -> 2-way conflicts (free). No barriers.
__global__ __launch_bounds__(64, 1) void crisp_partial16(const ushort* __restrict__ A16,
                                                         const ushort* __restrict__ W16T,
                                                         ushort* __restrict__ part) {
  __shared__ uint4 lsA[2][128];  // 32 rows x 4 granules
  __shared__ uint4 lsB[2][256];  // 64 cols x 4 granules

  const int lane = threadIdx.x;
  const int mg = lane >> 3;      // 0..7 -> rows mg*4 + r
  const int og = lane & 7;       // 0..7 -> cols og*8 + c
  const int row0 = blockIdx.y * BM;
  const int col0 = blockIdx.x * BO;
  const int kb0  = blockIdx.z * KPER;

  uint acc[4][8];
#pragma unroll
  for (int r = 0; r < 4; r++)
#pragma unroll
    for (int c = 0; c < 8; c++) acc[r][c] = 0xFC00FC00u;  // packed f16 -inf

  auto stage = [&](int buf, int kb) {
#pragma unroll
    for (int i = 0; i < 2; i++) {  // A: 128 granules
      int p = i * 64 + lane;
      int row = p >> 2, s = p & 3;
      int q = s ^ ((row >> 2) & 3);
      gload16(A16 + (size_t)(row0 + row) * INF_ + kb + q * 8, &lsA[buf][i * 64]);
    }
#pragma unroll
    for (int i = 0; i < 4; i++) {  // B: 256 granules
      int p = i * 64 + lane;
      int col = p >> 2, s = p & 3;
      int q = s ^ ((col >> 3) & 3);
      gload16(W16T + (size_t)(col0 + col) * INF_ + kb + q * 8, &lsB[buf][i * 64]);
    }
  };

  auto compute = [&](int buf) {
#pragma unroll
    for (int kq = 0; kq < 4; kq++) {
      uint4 av[4];
#pragma unroll
      for (int r = 0; r < 4; r++)
        av[r] = lsA[buf][(mg * 4 + r) * 4 + (kq ^ (mg & 3))];
      uint4 bv[8];
#pragma unroll
      for (int c = 0; c < 8; c++)
        bv[c] = lsB[buf][(og * 8 + c) * 4 + (kq ^ (og & 3))];
#pragma unroll
      for (int r = 0; r < 4; r++)
#pragma unroll
        for (int c = 0; c < 8; c++) {
          uint t0, t1, t2, t3;
          PKMIN(t0, av[r].x, bv[c].x);
          PKMIN(t1, av[r].y, bv[c].y);
          PKMIN(t2, av[r].z, bv[c].z);
          PKMIN(t3, av[r].w, bv[c].w);
          PKMAX(t0, t0, t1);
          PKMAX(t2, t2, t3);
          PKMAX(t0, t0, t2);
          PKMAXA(acc[r][c], t0);
        }
    }
  };

  stage(0, kb0);
  stage(1, kb0 + BK);
  asm volatile("s_waitcnt vmcnt(6)" ::: "memory");  // buf0 landed, buf1 in flight
  compute(0);
  asm volatile("s_waitcnt vmcnt(0)" ::: "memory");
  compute(1);

  // epilogue: fold packed (even,odd) halves, store f16 partial row of 8
  ushort* pout = part + (size_t)blockIdx.z * (BATCH * OUTF);
#pragma unroll
  for (int r = 0; r < 4; r++) {
    uint w[4];
#pragma unroll
    for (int cp = 0; cp < 4; cp++) {
      uint x0 = acc[r][2 * cp], x1 = acc[r][2 * cp + 1];
      uint h0 = x0 >> 16, h1 = x1 >> 16, m0, m1;
      PKMAX(m0, x0, h0);  // low half = max(lo,hi)
      PKMAX(m1, x1, h1);
      w[cp] = (m0 & 0xFFFFu) | (m1 << 16);
    }
    int row = row0 + mg * 4 + r;
    int col = col0 + og * 8;
    *(uint4*)(pout + (size_t)row * OUTF + col) = make_uint4(w[0], w[1], w[2], w[3]);
  }
}

// ---- pass 3: combine KS f16 planes -> f32 out ----
__global__ __launch_bounds__(256) void crisp_combine16(const uint4* __restrict__ part,
                                                       float* __restrict__ out) {
  int gid = blockIdx.x * 256 + threadIdx.x;  // 65536 threads x 8 outputs
  uint4 v = part[gid];
#pragma unroll
  for (int p = 1; p < KS; p++) {
    uint4 u = part[(size_t)p * 65536 + gid];
    PKMAXA(v.x, u.x); PKMAXA(v.y, u.y); PKMAXA(v.z, u.z); PKMAXA(v.w, u.w);
  }
  float4 o0 = make_float4(h2f(v.x), h2f(v.x >> 16), h2f(v.y), h2f(v.y >> 16));
  float4 o1 = make_float4(h2f(v.z), h2f(v.z >> 16), h2f(v.w), h2f(v.w >> 16));
  ((float4*)out)[gid * 2]     = o0;
  ((float4*)out)[gid * 2 + 1] = o1;
}

// ---- fallback (ws too small): naive, correct, slow; never expected to run ----
__global__ __launch_bounds__(256) void crisp_naive(const float* __restrict__ M,
                                                   const float* __restrict__ W,
                                                   float* __restrict__ out) {
  int o = blockIdx.x * 256 + threadIdx.x;
  int b = o >> 8, c = o & 255;
  float m = -1e30f;
  for (int k = 0; k < INF_; k++) m = fmaxf(m, fminf(M[(size_t)b * INF_ + k], W[(size_t)k * OUTF + c]));
  out[o] = m;
}

extern "C" void kernel_launch(void* const* d_in, const int* in_sizes, int n_in,
                              void* d_out, int out_size, void* d_ws, size_t ws_size,
                              hipStream_t stream) {
  const float* M = (const float*)d_in[0];
  const float* W = (const float*)d_in[1];
  float* out = (float*)d_out;

  if (ws_size >= WS_NEED) {
    ushort* A16  = (ushort*)((char*)d_ws + A16_OFF);
    ushort* W16T = (ushort*)((char*)d_ws + W16T_OFF);
    ushort* part = (ushort*)((char*)d_ws + PART_OFF);
    crisp_convert<<<544, 256, 0, stream>>>(M, W, A16, W16T);
    crisp_partial16<<<dim3(OUTF / BO, BATCH / BM, KS), 64, 0, stream>>>(A16, W16T, part);
    crisp_combine16<<<256, 256, 0, stream>>>((const uint4*)part, out);
  } else {
    crisp_naive<<<(BATCH * OUTF) / 256, 256, 0, stream>>>(M, W, out);
  }
}